// Round 19
// baseline (232.390 us; speedup 1.0000x reference)
//
#include <hip/hip_runtime.h>

#define BATCH 8
#define NPTS 4096
#define NROWS (BATCH*NPTS)   // 32768
#define KNB 16
#define NC 128

typedef __attribute__((ext_vector_type(8))) short bf16x8;
typedef __attribute__((ext_vector_type(2))) float f32x2;
typedef __attribute__((ext_vector_type(4))) float f32x4;
typedef __attribute__((ext_vector_type(16))) float f32x16;
typedef __attribute__((ext_vector_type(4))) unsigned int u32x4;
typedef __attribute__((ext_vector_type(2))) unsigned int u32x2;

static __device__ __forceinline__ unsigned short f2bf(float f) {
  unsigned u = __float_as_uint(f);
  u = u + 0x7fffu + ((u >> 16) & 1u);   // round-to-nearest-even
  return (unsigned short)(u >> 16);
}

static __device__ __forceinline__ unsigned cvtpk(float lo, float hi) {
  unsigned r;
  asm("v_cvt_pk_bf16_f32 %0, %1, %2" : "=v"(r) : "v"(lo), "v"(hi));
  return r;
}

template<int CTRL>
static __device__ __forceinline__ float dppmax(float v) {
  int mv = __builtin_amdgcn_update_dpp(0, __float_as_int(v), CTRL, 0xf, 0xf, true);
  return fmaxf(v, __int_as_float(mv));
}

static __device__ __forceinline__ unsigned int f2ord(float f) {
  int t = __float_as_int(f);
  return (unsigned int)(t ^ ((t >> 31) | 0x80000000));
}

// ---------------------------------------------------------------- prep
// Pair-SoA layout per batch: XY[m]={x2m,x2m+1,y2m,y2m+1}, ZW[m]={z.., w..}
// (w = |p|^2).
__global__ __launch_bounds__(256) void prep_kernel(
    const float* __restrict__ xyz, const float* __restrict__ W0,
    const float* __restrict__ W1, const float* __restrict__ W2,
    float4* __restrict__ XYp, float4* __restrict__ ZWp,
    unsigned short* __restrict__ W1bf, unsigned short* __restrict__ W2bf,
    unsigned short* __restrict__ W0p)
{
  int i = blockIdx.x * 256 + threadIdx.x;
  if (i < NROWS) {
    #pragma clang fp contract(off)
    float x = xyz[3*i], y = xyz[3*i+1], z = xyz[3*i+2];
    float sq = x*x + y*y + z*z;
    float px = __shfl_xor(x, 1);
    float py = __shfl_xor(y, 1);
    float pz = __shfl_xor(z, 1);
    float pw = __shfl_xor(sq, 1);
    int bb   = i >> 12;
    int pairi = (i & (NPTS-1)) >> 1;
    if ((i & 1) == 0) XYp[(size_t)bb*2048 + pairi] = make_float4(x, px, y, py);
    else              ZWp[(size_t)bb*2048 + pairi] = make_float4(pz, z, pw, sq);
  }
  if (i < NC*NC) {
    W1bf[i] = f2bf(W1[i]);
    W2bf[i] = f2bf(W2[i]);
  }
  if (i < NC) {
    // split-precision padded W0: [128][16] bf16
    #pragma unroll
    for (int c = 0; c < 3; ++c) {
      float v = W0[i*3 + c];
      unsigned short hi = f2bf(v);
      float lof = v - __uint_as_float((unsigned)hi << 16);
      unsigned short lo = f2bf(lof);
      W0p[i*16 + c]     = hi;
      W0p[i*16 + 3 + c] = hi;
      W0p[i*16 + 6 + c] = lo;
    }
    #pragma unroll
    for (int c = 9; c < 16; ++c) W0p[i*16 + c] = 0;
  }
}

// ---------------------------------------------------------------- topk (v15)
// R13-proven streaming structure + GROUP-SCREENED second pass: pass 1
// tracks 8 per-group packed maxima (16 VGPRs of accumulated state — not
// rematerializable); tmf = radix 17th-of-lane-maxima (v1 = fold of group
// maxima -> bit-identical threshold). Pass 2 rescans ONLY groups whose max
// >= tmf (exact screen, no false negatives): ~25 of 512 (lane,group) cells
// -> pass-2 traffic ~3KB/wave instead of 64KB. Selection: atomic-slot +
// rank over uint64 keys (proven) -> output bit-identical.
__global__ __launch_bounds__(256, 4) void topk_kernel(
    const float4* __restrict__ XYp, const float4* __restrict__ ZWp,
    float4* __restrict__ grouped4)
{
  __shared__ unsigned long long ck_s[4][64];
  __shared__ unsigned int      cnt_s[4];

  const int lane = threadIdx.x & 63;
  const int w    = threadIdx.x >> 6;
  const int wid  = blockIdx.x * 4 + w;
  const int b    = wid >> 12;
  const int m    = wid & (NPTS - 1);
  const float4* XYb = XYp + (size_t)b * 2048;
  const float4* ZWb = ZWp + (size_t)b * 2048;

  if (lane == 0) cnt_s[w] = 0;    // DS ops of a wave execute in order

  // query point m from pair arrays
  float4 mxy = XYb[m >> 1];
  float4 mzw = ZWb[m >> 1];
  const int mo = m & 1;
  const float pmx = mo ? mxy.y : mxy.x;
  const float pmy = mo ? mxy.w : mxy.z;
  const float pmz = mo ? mzw.y : mzw.x;
  const float pmw = mo ? mzw.w : mzw.z;

  const f32x2 pmx2 = {pmx, pmx};
  const f32x2 pmy2 = {pmy, pmy};
  const f32x2 pmz2 = {pmz, pmz};
  const f32x2 pmw2 = {pmw, pmw};
  const f32x2 two2 = {2.0f, 2.0f};

  // packed distance (bit-exact: left-assoc, contract off)
  auto distp = [&](const float4& xy, const float4& zw) -> f32x2 {
    #pragma clang fp contract(off)
    f32x2 xx = {xy.x, xy.y}, yy = {xy.z, xy.w};
    f32x2 zz = {zw.x, zw.y}, ww = {zw.z, zw.w};
    f32x2 ax = pmx2 * xx;
    f32x2 by = pmy2 * yy;
    f32x2 s1 = ax + by;
    f32x2 cz = pmz2 * zz;
    f32x2 dot = s1 + cz;          // pm.x*x + pm.y*y + pm.z*z
    f32x2 sw  = pmw2 + ww;        // sq_m + sq_n
    f32x2 td  = two2 * dot;       // 2*dot
    return sw - td;               // (sq_m+sq_n) - 2*dot
  };

  auto push = [&](float d, int n) {
    unsigned old = atomicAdd(&cnt_s[w], 1u);
    if (old < 64)
      ck_s[w][old] = ((unsigned long long)f2ord(d) << 12)
                   | (unsigned)(4095 - n);
  };

  // ---- pass 1: streaming, 8 per-group packed maxima (group = 4 j2-iters)
  f32x2 g2[8];
  #pragma unroll
  for (int g = 0; g < 8; ++g) g2[g] = (f32x2){-3.0e38f, -3.0e38f};

  #pragma unroll
  for (int j2 = 0; j2 < 32; ++j2) {
    f32x2 dd = distp(XYb[j2*64 + lane], ZWb[j2*64 + lane]);
    g2[j2 >> 2] = __builtin_elementwise_max(g2[j2 >> 2], dd);
  }

  // lane max = fold of group maxima (exact)
  f32x2 m2 = g2[0];
  #pragma unroll
  for (int g = 1; g < 8; ++g) m2 = __builtin_elementwise_max(m2, g2[g]);
  const float v1 = fmaxf(m2.x, m2.y);

  // ---- exact 17th largest of the 64 lane maxima (radix over ordered uint)
  unsigned u1 = f2ord(v1);
  unsigned cur = 0u;
  #pragma unroll 1
  for (int bit = 31; bit >= 0; --bit) {
    unsigned cand = cur | (1u << bit);
    if (__popcll(__ballot(u1 >= cand)) >= 17) cur = cand;
  }
  unsigned ob = (cur & 0x80000000u) ? (cur ^ 0x80000000u) : ~cur;
  const float tmf = __uint_as_float(ob);
  // tmf <= true 17th largest of all 4096; count(d >= tmf) >= 17.

  // ---- pass 2: GROUP-SCREENED rescan (exec-masked; ~25/512 cells active)
  #pragma unroll
  for (int g = 0; g < 8; ++g) {
    if (fmaxf(g2[g].x, g2[g].y) >= tmf) {
      #pragma unroll
      for (int jj = 0; jj < 4; ++jj) {
        const int j2 = g*4 + jj;
        f32x2 dd = distp(XYb[j2*64 + lane], ZWb[j2*64 + lane]);
        int n0 = (j2*64 + lane) << 1;
        if (dd.x >= tmf) push(dd.x, n0);
        if (dd.y >= tmf) push(dd.y, n0 | 1);
      }
    }
  }

  int ctot = (int)cnt_s[w];        // in-order DS read after the pushes
  if (ctot > 64) ctot = 64;

  // ---- own one candidate per lane; rank it against all (broadcast reads)
  unsigned long long myk = ck_s[w][lane];
  int rank = 0;
  #pragma unroll
  for (int c2 = 0; c2 < 32; ++c2) {
    unsigned long long kc = ck_s[w][c2];
    rank += (c2 < ctot && kc > myk) ? 1 : 0;
  }
  if (ctot > 32) {            // wave-uniform
    #pragma unroll
    for (int c2 = 32; c2 < 64; ++c2) {
      unsigned long long kc = ck_s[w][c2];
      rank += (c2 < ctot && kc > myk) ? 1 : 0;
    }
  }

  // ---- ranks 1..16: gather coords, write at slot rank-1
  if (lane < ctot && rank >= 1 && rank <= KNB) {
    int sn = 4095 - (int)(myk & 0xFFFull);
    float4 gxy = XYb[sn >> 1];
    float4 gzw = ZWb[sn >> 1];
    int o = sn & 1;
    grouped4[(size_t)wid * KNB + (rank - 1)] =
        make_float4(o ? gxy.y : gxy.x, o ? gxy.w : gxy.z,
                    o ? gzw.y : gzw.x, o ? gzw.w : gzw.z);
  }
}

// ---------------------------------------------------------------- mlp (v2.1)
// (unchanged — R9-proven 16-points/block version)
static __device__ __forceinline__ f32x16 zero16() {
  f32x16 v;
  #pragma unroll
  for (int i = 0; i < 16; ++i) v[i] = 0.0f;
  return v;
}

static __device__ __forceinline__ void epi_pack(
    const f32x16 (&acc)[2][4], const float* __restrict__ bias,
    int h, u32x4 (&bfrag)[2][8])
{
  #pragma unroll
  for (int tt = 0; tt < 4; ++tt) {
    float4 bb[4];
    #pragma unroll
    for (int q = 0; q < 4; ++q)
      bb[q] = *(const float4*)&bias[32*tt + 8*q + 4*h];
    #pragma unroll
    for (int nt = 0; nt < 2; ++nt) {
      unsigned P[8];
      #pragma unroll
      for (int q = 0; q < 4; ++q) {
        float v0 = fmaxf(acc[nt][tt][4*q+0] + bb[q].x, 0.f);
        float v1 = fmaxf(acc[nt][tt][4*q+1] + bb[q].y, 0.f);
        float v2 = fmaxf(acc[nt][tt][4*q+2] + bb[q].z, 0.f);
        float v3 = fmaxf(acc[nt][tt][4*q+3] + bb[q].w, 0.f);
        P[2*q]   = cvtpk(v0, v1);
        P[2*q+1] = cvtpk(v2, v3);
      }
      u32x2 s0 = __builtin_amdgcn_permlane32_swap(P[0], P[2], false, false);
      u32x2 s1 = __builtin_amdgcn_permlane32_swap(P[1], P[3], false, false);
      bfrag[nt][2*tt]   = (u32x4){s0.x, s1.x, s0.y, s1.y};
      u32x2 s2 = __builtin_amdgcn_permlane32_swap(P[4], P[6], false, false);
      u32x2 s3 = __builtin_amdgcn_permlane32_swap(P[5], P[7], false, false);
      bfrag[nt][2*tt+1] = (u32x4){s2.x, s3.x, s2.y, s3.y};
    }
  }
}

static __device__ __forceinline__ void layer_mfma(
    const unsigned short* wl, int l31, int h,
    const u32x4 (&bfrag)[2][8], f32x16 (&acc)[2][4])
{
  const int swz = (l31 & 7) << 4;
  #pragma unroll
  for (int tt = 0; tt < 4; ++tt) {
    const int row = 32*tt + l31;
    #pragma unroll
    for (int f = 0; f < 8; ++f) {
      bf16x8 a = *(const bf16x8*)&wl[row*128 + (((f*32 + h*16) ^ swz) >> 1)];
      acc[0][tt] = __builtin_amdgcn_mfma_f32_32x32x16_bf16(
          a, __builtin_bit_cast(bf16x8, bfrag[0][f]), acc[0][tt], 0, 0, 0);
      acc[1][tt] = __builtin_amdgcn_mfma_f32_32x32x16_bf16(
          a, __builtin_bit_cast(bf16x8, bfrag[1][f]), acc[1][tt], 0, 0, 0);
    }
  }
}

__global__ __launch_bounds__(256) void mlp_kernel(
    const float4* __restrict__ grouped4,
    const unsigned short* __restrict__ W0p, const float* __restrict__ b0,
    const unsigned short* __restrict__ W1bf, const float* __restrict__ b1,
    const unsigned short* __restrict__ W2bf, const float* __restrict__ b2,
    float* __restrict__ out)
{
  __shared__ unsigned short wlds[2*NC*NC];   // 64 KB: W1 | W2, XOR-swizzled rows

  const int t    = threadIdx.x;
  const int lane = t & 63;
  const int w    = t >> 6;
  const int l31  = lane & 31;
  const int h    = lane >> 5;

  #pragma unroll
  for (int it = 0; it < 16; ++it) {
    int e8 = (it*256 + t) * 8;
    const unsigned short* src = (it < 8) ? (W1bf + e8) : (W2bf + (e8 - NC*NC));
    u32x4 v = *(const u32x4*)src;
    int el  = e8 & (NC*NC - 1);
    int row = el >> 7;
    int cb  = (el & 127) * 2;
    int dst = (e8 & (NC*NC)) + row*128 + (((cb ^ ((row & 7) << 4))) >> 1);
    *(u32x4*)&wlds[dst] = v;
  }
  __syncthreads();

  const int rbase = blockIdx.x*256 + w*64;
  const int pbase = blockIdx.x*16  + w*4;

  float4 g0 = grouped4[rbase + l31];
  float4 g1 = grouped4[rbase + 32 + l31];

  auto mkb0 = [&](const float4& g) -> bf16x8 {
    unsigned short hx = f2bf(g.x), hy = f2bf(g.y), hz = f2bf(g.z);
    float lxf = g.x - __uint_as_float((unsigned)hx << 16);
    float lyf = g.y - __uint_as_float((unsigned)hy << 16);
    float lzf = g.z - __uint_as_float((unsigned)hz << 16);
    unsigned short lx = f2bf(lxf), ly = f2bf(lyf), lz = f2bf(lzf);
    unsigned hxy = (unsigned)hx | ((unsigned)hy << 16);
    u32x4 B;
    B.x = h ? (unsigned)hz : hxy;
    B.y = h ? 0u : ((unsigned)hz | ((unsigned)lx << 16));
    B.z = h ? 0u : ((unsigned)ly | ((unsigned)lz << 16));
    B.w = h ? 0u : hxy;
    return __builtin_bit_cast(bf16x8, B);
  };
  bf16x8 bf0n0 = mkb0(g0);
  bf16x8 bf0n1 = mkb0(g1);

  f32x16 acc[2][4];
  #pragma unroll
  for (int nt = 0; nt < 2; ++nt)
    #pragma unroll
    for (int tt = 0; tt < 4; ++tt) acc[nt][tt] = zero16();

  #pragma unroll
  for (int tt = 0; tt < 4; ++tt) {
    bf16x8 a = *(const bf16x8*)&W0p[(32*tt + l31)*16 + 8*h];
    acc[0][tt] = __builtin_amdgcn_mfma_f32_32x32x16_bf16(a, bf0n0, acc[0][tt], 0, 0, 0);
    acc[1][tt] = __builtin_amdgcn_mfma_f32_32x32x16_bf16(a, bf0n1, acc[1][tt], 0, 0, 0);
  }

  u32x4 bfrag[2][8];
  epi_pack(acc, b0, h, bfrag);

  #pragma unroll
  for (int nt = 0; nt < 2; ++nt)
    #pragma unroll
    for (int tt = 0; tt < 4; ++tt) acc[nt][tt] = zero16();
  layer_mfma(&wlds[0], l31, h, bfrag, acc);

  epi_pack(acc, b1, h, bfrag);

  #pragma unroll
  for (int nt = 0; nt < 2; ++nt)
    #pragma unroll
    for (int tt = 0; tt < 4; ++tt) acc[nt][tt] = zero16();
  layer_mfma(&wlds[NC*NC], l31, h, bfrag, acc);

  const int oR = 8*((lane >> 2) & 3) + 4*h + (lane & 3);
  float b2v[4];
  #pragma unroll
  for (int tt = 0; tt < 4; ++tt) b2v[tt] = b2[32*tt + oR];

  #pragma unroll
  for (int nt = 0; nt < 2; ++nt) {
    const int p = pbase + 2*nt + ((lane >> 4) & 1);
    #pragma unroll
    for (int tt = 0; tt < 4; ++tt) {
      float m[16];
      #pragma unroll
      for (int r = 0; r < 16; ++r) {
        float v = acc[nt][tt][r];
        v = dppmax<0xB1>(v);
        v = dppmax<0x4E>(v);
        v = dppmax<0x124>(v);
        v = dppmax<0x128>(v);
        m[r] = v;
      }
      float sel = m[0];
      #pragma unroll
      for (int r = 1; r < 16; ++r) sel = ((lane & 15) == r) ? m[r] : sel;
      out[(size_t)p*128 + 32*tt + oR] = sel + b2v[tt];
    }
  }
}

// ---------------------------------------------------------------- launch
extern "C" void kernel_launch(void* const* d_in, const int* in_sizes, int n_in,
                              void* d_out, int out_size, void* d_ws, size_t ws_size,
                              hipStream_t stream) {
  const float* xyz = (const float*)d_in[0];
  const float* W0  = (const float*)d_in[1];
  const float* b0  = (const float*)d_in[2];
  const float* W1  = (const float*)d_in[3];
  const float* b1  = (const float*)d_in[4];
  const float* W2  = (const float*)d_in[5];
  const float* b2  = (const float*)d_in[6];
  float* out = (float*)d_out;

  char* ws = (char*)d_ws;
  float4* XYp      = (float4*)ws;                              // 256 KB
  float4* ZWp      = (float4*)(ws + (size_t)BATCH*2048*16);    // 256 KB
  float4* grouped4 = (float4*)(ws + (size_t)NROWS*16);         // 8 MB
  unsigned short* W1bf = (unsigned short*)(ws + (size_t)NROWS*16 + (size_t)NROWS*KNB*16);
  unsigned short* W2bf = W1bf + NC*NC;                         // 32 KB each
  unsigned short* W0p  = W2bf + NC*NC;                         // 4 KB

  prep_kernel<<<NROWS/256, 256, 0, stream>>>(xyz, W0, W1, W2, XYp, ZWp, W1bf, W2bf, W0p);
  topk_kernel<<<NROWS/4, 256, 0, stream>>>(XYp, ZWp, grouped4);
  mlp_kernel<<<NROWS/16, 256, 0, stream>>>(grouped4, W0p, b0, W1bf, b1, W2bf, b2, out);
}

// Round 20
// 147.561 us; speedup vs baseline: 1.5749x; 1.5749x over previous
//
#include <hip/hip_runtime.h>

#define BATCH 8
#define NPTS 4096
#define NROWS (BATCH*NPTS)   // 32768
#define KNB 16
#define NC 128

typedef __attribute__((ext_vector_type(8))) short bf16x8;
typedef __attribute__((ext_vector_type(2))) float f32x2;
typedef __attribute__((ext_vector_type(4))) float f32x4;
typedef __attribute__((ext_vector_type(16))) float f32x16;
typedef __attribute__((ext_vector_type(4))) unsigned int u32x4;
typedef __attribute__((ext_vector_type(2))) unsigned int u32x2;

static __device__ __forceinline__ unsigned short f2bf(float f) {
  unsigned u = __float_as_uint(f);
  u = u + 0x7fffu + ((u >> 16) & 1u);   // round-to-nearest-even
  return (unsigned short)(u >> 16);
}

static __device__ __forceinline__ unsigned cvtpk(float lo, float hi) {
  unsigned r;
  asm("v_cvt_pk_bf16_f32 %0, %1, %2" : "=v"(r) : "v"(lo), "v"(hi));
  return r;
}

template<int CTRL>
static __device__ __forceinline__ float dppmax(float v) {
  int mv = __builtin_amdgcn_update_dpp(0, __float_as_int(v), CTRL, 0xf, 0xf, true);
  return fmaxf(v, __int_as_float(mv));
}

static __device__ __forceinline__ unsigned int f2ord(float f) {
  int t = __float_as_int(f);
  return (unsigned int)(t ^ ((t >> 31) | 0x80000000));
}

// ---------------------------------------------------------------- prep
// Pair-SoA layout per batch: XY[m]={x2m,x2m+1,y2m,y2m+1}, ZW[m]={z.., w..}
// (w = |p|^2).
__global__ __launch_bounds__(256) void prep_kernel(
    const float* __restrict__ xyz, const float* __restrict__ W0,
    const float* __restrict__ W1, const float* __restrict__ W2,
    float4* __restrict__ XYp, float4* __restrict__ ZWp,
    unsigned short* __restrict__ W1bf, unsigned short* __restrict__ W2bf,
    unsigned short* __restrict__ W0p)
{
  int i = blockIdx.x * 256 + threadIdx.x;
  if (i < NROWS) {
    #pragma clang fp contract(off)
    float x = xyz[3*i], y = xyz[3*i+1], z = xyz[3*i+2];
    float sq = x*x + y*y + z*z;
    float px = __shfl_xor(x, 1);
    float py = __shfl_xor(y, 1);
    float pz = __shfl_xor(z, 1);
    float pw = __shfl_xor(sq, 1);
    int bb   = i >> 12;
    int pairi = (i & (NPTS-1)) >> 1;
    if ((i & 1) == 0) XYp[(size_t)bb*2048 + pairi] = make_float4(x, px, y, py);
    else              ZWp[(size_t)bb*2048 + pairi] = make_float4(pz, z, pw, sq);
  }
  if (i < NC*NC) {
    W1bf[i] = f2bf(W1[i]);
    W2bf[i] = f2bf(W2[i]);
  }
  if (i < NC) {
    // split-precision padded W0: [128][16] bf16
    #pragma unroll
    for (int c = 0; c < 3; ++c) {
      float v = W0[i*3 + c];
      unsigned short hi = f2bf(v);
      float lof = v - __uint_as_float((unsigned)hi << 16);
      unsigned short lo = f2bf(lof);
      W0p[i*16 + c]     = hi;
      W0p[i*16 + 3 + c] = hi;
      W0p[i*16 + 6 + c] = lo;
    }
    #pragma unroll
    for (int c = 9; c < 16; ++c) W0p[i*16 + c] = 0;
  }
}

// ---------------------------------------------------------------- topk (v13)
// EXACT revert to the R17-proven kernel (97.9us best): half-stored
// single-pass + atomic-slot + rank selection.
__global__ __launch_bounds__(256, 4) void topk_kernel(
    const float4* __restrict__ XYp, const float4* __restrict__ ZWp,
    float4* __restrict__ grouped4)
{
  __shared__ unsigned long long ck_s[4][64];
  __shared__ unsigned int      cnt_s[4];

  const int lane = threadIdx.x & 63;
  const int w    = threadIdx.x >> 6;
  const int wid  = blockIdx.x * 4 + w;
  const int b    = wid >> 12;
  const int m    = wid & (NPTS - 1);
  const float4* XYb = XYp + (size_t)b * 2048;
  const float4* ZWb = ZWp + (size_t)b * 2048;

  if (lane == 0) cnt_s[w] = 0;    // DS ops of a wave execute in order

  // query point m from pair arrays
  float4 mxy = XYb[m >> 1];
  float4 mzw = ZWb[m >> 1];
  const int mo = m & 1;
  const float pmx = mo ? mxy.y : mxy.x;
  const float pmy = mo ? mxy.w : mxy.z;
  const float pmz = mo ? mzw.y : mzw.x;
  const float pmw = mo ? mzw.w : mzw.z;

  const f32x2 pmx2 = {pmx, pmx};
  const f32x2 pmy2 = {pmy, pmy};
  const f32x2 pmz2 = {pmz, pmz};
  const f32x2 pmw2 = {pmw, pmw};
  const f32x2 two2 = {2.0f, 2.0f};

  // packed distance (bit-exact: left-assoc, contract off)
  auto distp = [&](const float4& xy, const float4& zw) -> f32x2 {
    #pragma clang fp contract(off)
    f32x2 xx = {xy.x, xy.y}, yy = {xy.z, xy.w};
    f32x2 zz = {zw.x, zw.y}, ww = {zw.z, zw.w};
    f32x2 ax = pmx2 * xx;
    f32x2 by = pmy2 * yy;
    f32x2 s1 = ax + by;
    f32x2 cz = pmz2 * zz;
    f32x2 dot = s1 + cz;          // pm.x*x + pm.y*y + pm.z*z
    f32x2 sw  = pmw2 + ww;        // sq_m + sq_n
    f32x2 td  = two2 * dot;       // 2*dot
    return sw - td;               // (sq_m+sq_n) - 2*dot
  };

  // radix 17th-largest over a per-lane ordered uint (proven)
  auto radix17 = [&](unsigned u) -> float {
    unsigned cur = 0u;
    #pragma unroll 1
    for (int bit = 31; bit >= 0; --bit) {
      unsigned cand = cur | (1u << bit);
      if (__popcll(__ballot(u >= cand)) >= 17) cur = cand;
    }
    unsigned ob = (cur & 0x80000000u) ? (cur ^ 0x80000000u) : ~cur;
    return __uint_as_float(ob);
  };

  auto push = [&](float d, int n) {
    unsigned old = atomicAdd(&cnt_s[w], 1u);
    if (old < 64)
      ck_s[w][old] = ((unsigned long long)f2ord(d) << 12)
                   | (unsigned)(4095 - n);
  };

  // ---- half 1: compute and STORE d2[16] (32 VGPRs), track half lane-max
  f32x2 d2[16];
  #pragma unroll
  for (int j2 = 0; j2 < 16; ++j2)
    d2[j2] = distp(XYb[j2*64 + lane], ZWb[j2*64 + lane]);

  f32x2 mh = d2[0];
  #pragma unroll
  for (int j2 = 1; j2 < 16; ++j2)
    mh = __builtin_elementwise_max(mh, d2[j2]);
  const float v1h = fmaxf(mh.x, mh.y);

  // ---- T1 from first-half lane maxima: T1 <= true 17th-largest of all,
  //      and count(first half >= T1) >= 17  =>  valid candidate threshold
  const float t1f = radix17(f2ord(v1h));

  // ---- push half-1 candidates FROM REGISTERS
  #pragma unroll
  for (int j2 = 0; j2 < 16; ++j2) {
    int n0 = (j2*64 + lane) << 1;
    if (d2[j2].x >= t1f) push(d2[j2].x, n0);
    if (d2[j2].y >= t1f) push(d2[j2].y, n0 | 1);
  }

  // ---- half 2: stream, push inline (no storage), track full lane max
  float v1f = v1h;
  #pragma unroll
  for (int j2 = 16; j2 < 32; ++j2) {
    f32x2 dd = distp(XYb[j2*64 + lane], ZWb[j2*64 + lane]);
    int n0 = (j2*64 + lane) << 1;
    if (dd.x >= t1f) push(dd.x, n0);
    if (dd.y >= t1f) push(dd.y, n0 | 1);
    v1f = fmaxf(v1f, fmaxf(dd.x, dd.y));
  }

  int ctot = (int)cnt_s[w];        // in-order DS read after the pushes

  // ---- rare exact fallback (wave-uniform): T1 admitted > 64 candidates
  if (ctot > 64) {
    const float tmf = radix17(f2ord(v1f));   // exact full-max threshold
    if (lane == 0) cnt_s[w] = 0;
    #pragma unroll 1
    for (int j2 = 0; j2 < 16; ++j2) {
      int n0 = (j2*64 + lane) << 1;
      if (d2[j2].x >= tmf) push(d2[j2].x, n0);
      if (d2[j2].y >= tmf) push(d2[j2].y, n0 | 1);
    }
    #pragma unroll 1
    for (int j2 = 16; j2 < 32; ++j2) {
      f32x2 dd = distp(XYb[j2*64 + lane], ZWb[j2*64 + lane]);
      int n0 = (j2*64 + lane) << 1;
      if (dd.x >= tmf) push(dd.x, n0);
      if (dd.y >= tmf) push(dd.y, n0 | 1);
    }
    ctot = (int)cnt_s[w];
  }
  if (ctot > 64) ctot = 64;

  // ---- own one candidate per lane; rank it against all (broadcast reads)
  unsigned long long myk = ck_s[w][lane];
  int rank = 0;
  #pragma unroll
  for (int c2 = 0; c2 < 32; ++c2) {
    unsigned long long kc = ck_s[w][c2];
    rank += (c2 < ctot && kc > myk) ? 1 : 0;
  }
  if (ctot > 32) {            // wave-uniform
    #pragma unroll
    for (int c2 = 32; c2 < 64; ++c2) {
      unsigned long long kc = ck_s[w][c2];
      rank += (c2 < ctot && kc > myk) ? 1 : 0;
    }
  }

  // ---- ranks 1..16: gather coords, write at slot rank-1
  if (lane < ctot && rank >= 1 && rank <= KNB) {
    int sn = 4095 - (int)(myk & 0xFFFull);
    float4 gxy = XYb[sn >> 1];
    float4 gzw = ZWb[sn >> 1];
    int o = sn & 1;
    grouped4[(size_t)wid * KNB + (rank - 1)] =
        make_float4(o ? gxy.y : gxy.x, o ? gxy.w : gxy.z,
                    o ? gzw.y : gzw.x, o ? gzw.w : gzw.z);
  }
}

// ---------------------------------------------------------------- mlp (v4)
// R17 compute path, LDS halved: W1 and W2 staged SEQUENTIALLY into one
// 32 KB buffer (stage W1 -> L0+L1 -> barrier -> stage W2 -> barrier -> L2).
// Same staged bytes + 2 extra barriers, but 64->32 KB LDS doubles
// blocks/CU (2->4+) for latency hiding. Numerics byte-identical.
static __device__ __forceinline__ f32x16 zero16() {
  f32x16 v;
  #pragma unroll
  for (int i = 0; i < 16; ++i) v[i] = 0.0f;
  return v;
}

static __device__ __forceinline__ void epi_pack(
    const f32x16 (&acc)[2][4], const float* __restrict__ bias,
    int h, u32x4 (&bfrag)[2][8])
{
  #pragma unroll
  for (int tt = 0; tt < 4; ++tt) {
    float4 bb[4];
    #pragma unroll
    for (int q = 0; q < 4; ++q)
      bb[q] = *(const float4*)&bias[32*tt + 8*q + 4*h];
    #pragma unroll
    for (int nt = 0; nt < 2; ++nt) {
      unsigned P[8];
      #pragma unroll
      for (int q = 0; q < 4; ++q) {
        float v0 = fmaxf(acc[nt][tt][4*q+0] + bb[q].x, 0.f);
        float v1 = fmaxf(acc[nt][tt][4*q+1] + bb[q].y, 0.f);
        float v2 = fmaxf(acc[nt][tt][4*q+2] + bb[q].z, 0.f);
        float v3 = fmaxf(acc[nt][tt][4*q+3] + bb[q].w, 0.f);
        P[2*q]   = cvtpk(v0, v1);
        P[2*q+1] = cvtpk(v2, v3);
      }
      u32x2 s0 = __builtin_amdgcn_permlane32_swap(P[0], P[2], false, false);
      u32x2 s1 = __builtin_amdgcn_permlane32_swap(P[1], P[3], false, false);
      bfrag[nt][2*tt]   = (u32x4){s0.x, s1.x, s0.y, s1.y};
      u32x2 s2 = __builtin_amdgcn_permlane32_swap(P[4], P[6], false, false);
      u32x2 s3 = __builtin_amdgcn_permlane32_swap(P[5], P[7], false, false);
      bfrag[nt][2*tt+1] = (u32x4){s2.x, s3.x, s2.y, s3.y};
    }
  }
}

static __device__ __forceinline__ void layer_mfma(
    const unsigned short* wl, int l31, int h,
    const u32x4 (&bfrag)[2][8], f32x16 (&acc)[2][4])
{
  const int swz = (l31 & 7) << 4;
  #pragma unroll
  for (int tt = 0; tt < 4; ++tt) {
    const int row = 32*tt + l31;
    #pragma unroll
    for (int f = 0; f < 8; ++f) {
      bf16x8 a = *(const bf16x8*)&wl[row*128 + (((f*32 + h*16) ^ swz) >> 1)];
      acc[0][tt] = __builtin_amdgcn_mfma_f32_32x32x16_bf16(
          a, __builtin_bit_cast(bf16x8, bfrag[0][f]), acc[0][tt], 0, 0, 0);
      acc[1][tt] = __builtin_amdgcn_mfma_f32_32x32x16_bf16(
          a, __builtin_bit_cast(bf16x8, bfrag[1][f]), acc[1][tt], 0, 0, 0);
    }
  }
}

__global__ __launch_bounds__(256) void mlp_kernel(
    const float4* __restrict__ grouped4,
    const unsigned short* __restrict__ W0p, const float* __restrict__ b0,
    const unsigned short* __restrict__ W1bf, const float* __restrict__ b1,
    const unsigned short* __restrict__ W2bf, const float* __restrict__ b2,
    float* __restrict__ out)
{
  __shared__ unsigned short wlds[NC*NC];   // 32 KB: W1 then W2 (sequential)

  const int t    = threadIdx.x;
  const int lane = t & 63;
  const int w    = t >> 6;
  const int l31  = lane & 31;
  const int h    = lane >> 5;

  auto stage = [&](const unsigned short* W) {
    #pragma unroll
    for (int it = 0; it < 8; ++it) {
      int e8 = (it*256 + t) * 8;                 // linear short index
      u32x4 v = *(const u32x4*)(W + e8);
      int row = e8 >> 7;
      int cb  = (e8 & 127) * 2;
      int dst = row*128 + (((cb ^ ((row & 7) << 4))) >> 1);
      *(u32x4*)&wlds[dst] = v;
    }
  };

  // ---- stage W1 (LDS); L0 compute overlaps the stores
  stage(W1bf);

  const int rbase = blockIdx.x*256 + w*64;
  const int pbase = blockIdx.x*16  + w*4;

  float4 g0 = grouped4[rbase + l31];
  float4 g1 = grouped4[rbase + 32 + l31];

  auto mkb0 = [&](const float4& g) -> bf16x8 {
    unsigned short hx = f2bf(g.x), hy = f2bf(g.y), hz = f2bf(g.z);
    float lxf = g.x - __uint_as_float((unsigned)hx << 16);
    float lyf = g.y - __uint_as_float((unsigned)hy << 16);
    float lzf = g.z - __uint_as_float((unsigned)hz << 16);
    unsigned short lx = f2bf(lxf), ly = f2bf(lyf), lz = f2bf(lzf);
    unsigned hxy = (unsigned)hx | ((unsigned)hy << 16);
    u32x4 B;
    B.x = h ? (unsigned)hz : hxy;
    B.y = h ? 0u : ((unsigned)hz | ((unsigned)lx << 16));
    B.z = h ? 0u : ((unsigned)ly | ((unsigned)lz << 16));
    B.w = h ? 0u : hxy;
    return __builtin_bit_cast(bf16x8, B);
  };
  bf16x8 bf0n0 = mkb0(g0);
  bf16x8 bf0n1 = mkb0(g1);

  f32x16 acc[2][4];
  #pragma unroll
  for (int nt = 0; nt < 2; ++nt)
    #pragma unroll
    for (int tt = 0; tt < 4; ++tt) acc[nt][tt] = zero16();

  // ---- layer 0 (W0p from global; no LDS dependence)
  #pragma unroll
  for (int tt = 0; tt < 4; ++tt) {
    bf16x8 a = *(const bf16x8*)&W0p[(32*tt + l31)*16 + 8*h];
    acc[0][tt] = __builtin_amdgcn_mfma_f32_32x32x16_bf16(a, bf0n0, acc[0][tt], 0, 0, 0);
    acc[1][tt] = __builtin_amdgcn_mfma_f32_32x32x16_bf16(a, bf0n1, acc[1][tt], 0, 0, 0);
  }

  u32x4 bfrag[2][8];
  epi_pack(acc, b0, h, bfrag);

  __syncthreads();   // W1 staged

  // ---- layer 1
  #pragma unroll
  for (int nt = 0; nt < 2; ++nt)
    #pragma unroll
    for (int tt = 0; tt < 4; ++tt) acc[nt][tt] = zero16();
  layer_mfma(&wlds[0], l31, h, bfrag, acc);

  epi_pack(acc, b1, h, bfrag);

  __syncthreads();   // all waves done reading W1
  stage(W2bf);
  __syncthreads();   // W2 staged

  // ---- layer 2
  #pragma unroll
  for (int nt = 0; nt < 2; ++nt)
    #pragma unroll
    for (int tt = 0; tt < 4; ++tt) acc[nt][tt] = zero16();
  layer_mfma(&wlds[0], l31, h, bfrag, acc);

  const int oR = 8*((lane >> 2) & 3) + 4*h + (lane & 3);
  float b2v[4];
  #pragma unroll
  for (int tt = 0; tt < 4; ++tt) b2v[tt] = b2[32*tt + oR];

  #pragma unroll
  for (int nt = 0; nt < 2; ++nt) {
    const int p = pbase + 2*nt + ((lane >> 4) & 1);
    #pragma unroll
    for (int tt = 0; tt < 4; ++tt) {
      float m[16];
      #pragma unroll
      for (int r = 0; r < 16; ++r) {
        float v = acc[nt][tt][r];
        v = dppmax<0xB1>(v);
        v = dppmax<0x4E>(v);
        v = dppmax<0x124>(v);
        v = dppmax<0x128>(v);
        m[r] = v;
      }
      float sel = m[0];
      #pragma unroll
      for (int r = 1; r < 16; ++r) sel = ((lane & 15) == r) ? m[r] : sel;
      out[(size_t)p*128 + 32*tt + oR] = sel + b2v[tt];
    }
  }
}

// ---------------------------------------------------------------- launch
extern "C" void kernel_launch(void* const* d_in, const int* in_sizes, int n_in,
                              void* d_out, int out_size, void* d_ws, size_t ws_size,
                              hipStream_t stream) {
  const float* xyz = (const float*)d_in[0];
  const float* W0  = (const float*)d_in[1];
  const float* b0  = (const float*)d_in[2];
  const float* W1  = (const float*)d_in[3];
  const float* b1  = (const float*)d_in[4];
  const float* W2  = (const float*)d_in[5];
  const float* b2  = (const float*)d_in[6];
  float* out = (float*)d_out;

  char* ws = (char*)d_ws;
  float4* XYp      = (float4*)ws;                              // 256 KB
  float4* ZWp      = (float4*)(ws + (size_t)BATCH*2048*16);    // 256 KB
  float4* grouped4 = (float4*)(ws + (size_t)NROWS*16);         // 8 MB
  unsigned short* W1bf = (unsigned short*)(ws + (size_t)NROWS*16 + (size_t)NROWS*KNB*16);
  unsigned short* W2bf = W1bf + NC*NC;                         // 32 KB each
  unsigned short* W0p  = W2bf + NC*NC;                         // 4 KB

  prep_kernel<<<NROWS/256, 256, 0, stream>>>(xyz, W0, W1, W2, XYp, ZWp, W1bf, W2bf, W0p);
  topk_kernel<<<NROWS/4, 256, 0, stream>>>(XYp, ZWp, grouped4);
  mlp_kernel<<<NROWS/16, 256, 0, stream>>>(grouped4, W0p, b0, W1bf, b1, W2bf, b2, out);
}